// Round 10
// baseline (578.349 us; speedup 1.0000x reference)
//
#include <hip/hip_runtime.h>
#include <cstdint>

#define BB 256
#define TT 1000
#define DD 256
#define SS 10
#define HH 64
#define CC 100

// ---------------------------------------------------------------------------
// Kernel 1: input projection  xp[b,t,h] = 2*(x . W_ih + b_ih + b_hh)
// (R8's kc=64 form, known 128 us; R9's kc=32 regressed ~45 us -> reverted)
// ---------------------------------------------------------------------------
__global__ __launch_bounds__(256) void proj_kernel(
    const float* __restrict__ x, const float* __restrict__ W_ih,
    const float* __restrict__ b_ih, const float* __restrict__ b_hh,
    float* __restrict__ xp) {
  __shared__ float As[64][68];
  __shared__ float Bs[64][68];
  const int s = blockIdx.y;
  const int r0 = blockIdx.x * 64;
  const int tid = threadIdx.x;
  const int ty = tid >> 4, tx = tid & 15;
  const int ty4 = ty * 4, tx4 = tx * 4;
  float acc[4][4] = {{0.f, 0.f, 0.f, 0.f}};

  for (int kc = 0; kc < 4; ++kc) {
#pragma unroll
    for (int m = 0; m < 4; ++m) {
      int f = m * 256 + tid;
      int row = f >> 4, kq = f & 15;
      int r = r0 + row;
      int b = r / CC, c = r - b * CC;
      const float4 av = *(const float4*)(
          x + ((size_t)b * TT + s * CC + c) * DD + kc * 64 + kq * 4);
      *(float4*)&As[row][kq * 4] = av;
      const float4 wv = *(const float4*)(
          W_ih + ((size_t)s * HH + row) * DD + kc * 64 + kq * 4);
      *(float4*)&Bs[row][kq * 4] = wv;
    }
    __syncthreads();
#pragma unroll 4
    for (int k = 0; k < 64; k += 4) {
      float4 a[4], w[4];
#pragma unroll
      for (int i = 0; i < 4; ++i) a[i] = *(const float4*)&As[ty4 + i][k];
#pragma unroll
      for (int j = 0; j < 4; ++j) w[j] = *(const float4*)&Bs[tx4 + j][k];
#pragma unroll
      for (int i = 0; i < 4; ++i)
#pragma unroll
        for (int j = 0; j < 4; ++j)
          acc[i][j] += a[i].x * w[j].x + a[i].y * w[j].y +
                       a[i].z * w[j].z + a[i].w * w[j].w;
    }
    __syncthreads();
  }

  const float4 b1 = *(const float4*)(b_ih + s * HH + tx4);
  const float4 b2 = *(const float4*)(b_hh + s * HH + tx4);
#pragma unroll
  for (int i = 0; i < 4; ++i) {
    int r = r0 + ty4 + i;
    int b = r / CC, c = r - b * CC;
    float4 o;
    o.x = 2.f * (acc[i][0] + b1.x + b2.x);
    o.y = 2.f * (acc[i][1] + b1.y + b2.y);
    o.z = 2.f * (acc[i][2] + b1.z + b2.z);
    o.w = 2.f * (acc[i][3] + b1.w + b2.w);
    *(float4*)(xp + ((size_t)b * TT + s * CC + c) * HH + tx4) = o;
  }
}

// ---------------------------------------------------------------------------
// Kernel 2: recurrence + fused head. FAITHFUL copy of R6's probe<0> step loop
// (the empirical best: 239 us/rep), which R9's "improvements" regressed:
//   - hist[CC][68] row-walk (not single hrow)
//   - hv[16] array reads, compiler-scheduled, NO sched_barrier / NO asm
//   - R5-style xq0..3 ring with conditional per-slot reload
// plus the per-segment head fused back in (~3 us compute; removes the head
// kernel launch and 130 MB of ys HBM traffic).
// ---------------------------------------------------------------------------
__global__ __launch_bounds__(64, 1) void rnn_kernel(
    const float* __restrict__ xp, const float* __restrict__ W_hh,
    const float* __restrict__ fc_w, const float* __restrict__ fc_b,
    float* __restrict__ y) {
  __shared__ float hist[CC][68];
  const int b = blockIdx.x;
  const int lane = threadIdx.x;
  hist[CC - 1][lane] = 0.f;  // h0 = 0, read via cp at s=0,c=0

  float W[64];
  float h = 0.f;
  float4 hv[16];
  for (int s = 0; s < SS; ++s) {
    const float* wr = W_hh + ((size_t)s * HH + lane) * HH;
#pragma unroll
    for (int j = 0; j < 64; j += 4) {
      float4 v = *(const float4*)(wr + j);
      W[j] = 2.f * v.x; W[j + 1] = 2.f * v.y;
      W[j + 2] = 2.f * v.z; W[j + 3] = 2.f * v.w;
    }
    const float* xps = xp + ((size_t)b * TT + s * CC) * HH + lane;

    float xq0 = xps[0 * HH];
    float xq1 = xps[1 * HH];
    float xq2 = xps[2 * HH];
    float xq3 = xps[3 * HH];

    for (int c4 = 0; c4 < 25; ++c4) {
#pragma unroll
      for (int u = 0; u < 4; ++u) {
        const int c = c4 * 4 + u;
        const int cp = (c == 0) ? CC - 1 : c - 1;
        const float xv = (u == 0) ? xq0 : (u == 1) ? xq1 : (u == 2) ? xq2 : xq3;
#pragma unroll
        for (int j4 = 0; j4 < 16; ++j4)
          hv[j4] = *(const float4*)&hist[cp][j4 * 4];
        float a0 = xv, a1 = 0.f, a2 = 0.f, a3 = 0.f;
#pragma unroll
        for (int j4 = 0; j4 < 16; ++j4) {
          a0 += W[j4 * 4 + 0] * hv[j4].x;
          a1 += W[j4 * 4 + 1] * hv[j4].y;
          a2 += W[j4 * 4 + 2] * hv[j4].z;
          a3 += W[j4 * 4 + 3] * hv[j4].w;
        }
        float z2 = (a0 + a1) + (a2 + a3);  // = 2z (prescaled)
        float e = __expf(z2);
        h = 1.f - 2.f * __builtin_amdgcn_rcpf(e + 1.f);
        hist[c][lane] = h;
        if (c4 < 24) {
          const float xn = xps[(c + 4) * HH];
          if (u == 0) xq0 = xn;
          else if (u == 1) xq1 = xn;
          else if (u == 2) xq2 = xn;
          else xq3 = xn;
        }
      }
    }

    // fused head for this segment: lane l -> y[b, s*CC + l]
    const float fb = fc_b[s];
    const float* fw = fc_w + s * HH;  // wave-uniform
#pragma unroll
    for (int base = 0; base < CC; base += 64) {
      int l = base + lane;
      if (l < CC) {
        float z = fb;
#pragma unroll
        for (int i = 0; i < 64; i += 4) {
          float4 hvv = *(const float4*)&hist[l][i];
          z += hvv.x * fw[i] + hvv.y * fw[i + 1] + hvv.z * fw[i + 2] +
               hvv.w * fw[i + 3];
        }
        y[(size_t)b * TT + s * CC + l] =
            __builtin_amdgcn_rcpf(1.f + __expf(-z));
      }
    }
  }
}

// ---------------------------------------------------------------------------
// Kernel 3: CLOCK PROBE (diagnostic). 256 blocks x 1 wave; per block:
// 1000 iters x 64 independent v_add_f32 = 64K instrs = 128K issue-cycles.
// dur_us IS the clock readout: ~53us @2.4GHz, ~107us @1.2GHz.
// Its VALUBusy (~100% expected) also calibrates the gfx950 counter formula.
// Writes into xp scratch (dead after rnn_kernel).
// ---------------------------------------------------------------------------
__global__ __launch_bounds__(64, 1) void clock_probe(float* out) {
  const int tid = blockIdx.x * 64 + threadIdx.x;
  float a0 = out[tid] * 0.0f + 1.0f;
  float a1 = a0 + 1.f, a2 = a0 + 2.f, a3 = a0 + 3.f;
  float a4 = a0 + 4.f, a5 = a0 + 5.f, a6 = a0 + 6.f, a7 = a0 + 7.f;
  for (int i = 0; i < 1000; ++i) {
#pragma unroll
    for (int j = 0; j < 8; ++j) {
      a0 += a1; a1 += a2; a2 += a3; a3 += a4;
      a4 += a5; a5 += a6; a6 += a7; a7 += a0;
    }
  }
  out[tid] = a0 + a1 + a2 + a3 + a4 + a5 + a6 + a7;
}

extern "C" void kernel_launch(void* const* d_in, const int* in_sizes, int n_in,
                              void* d_out, int out_size, void* d_ws,
                              size_t ws_size, hipStream_t stream) {
  const float* x    = (const float*)d_in[0];
  const float* W_ih = (const float*)d_in[1];
  const float* W_hh = (const float*)d_in[2];
  const float* b_ih = (const float*)d_in[3];
  const float* b_hh = (const float*)d_in[4];
  const float* fc_w = (const float*)d_in[5];
  const float* fc_b = (const float*)d_in[6];
  float* y  = (float*)d_out;
  float* xp = (float*)d_ws;  // [B][T][H] fp32 = 65.5 MB

  proj_kernel<<<dim3(400, 10), 256, 0, stream>>>(x, W_ih, b_ih, b_hh, xp);
  rnn_kernel<<<256, 64, 0, stream>>>(xp, W_hh, fc_w, fc_b, y);
  clock_probe<<<256, 64, 0, stream>>>(xp);  // diagnostic; xp dead here
}

// Round 11
// 400.040 us; speedup vs baseline: 1.4457x; 1.4457x over previous
//
#include <hip/hip_runtime.h>
#include <cstdint>

#define BB 256
#define TT 1000
#define DD 256
#define SS 10
#define HH 64
#define CC 100

// ---------------------------------------------------------------------------
// Kernel 1: input projection  xp[b,t,h] = 2*(x . W_ih + b_ih + b_hh)
// (unchanged; known 128 us)
// ---------------------------------------------------------------------------
__global__ __launch_bounds__(256) void proj_kernel(
    const float* __restrict__ x, const float* __restrict__ W_ih,
    const float* __restrict__ b_ih, const float* __restrict__ b_hh,
    float* __restrict__ xp) {
  __shared__ float As[64][68];
  __shared__ float Bs[64][68];
  const int s = blockIdx.y;
  const int r0 = blockIdx.x * 64;
  const int tid = threadIdx.x;
  const int ty = tid >> 4, tx = tid & 15;
  const int ty4 = ty * 4, tx4 = tx * 4;
  float acc[4][4] = {{0.f, 0.f, 0.f, 0.f}};

  for (int kc = 0; kc < 4; ++kc) {
#pragma unroll
    for (int m = 0; m < 4; ++m) {
      int f = m * 256 + tid;
      int row = f >> 4, kq = f & 15;
      int r = r0 + row;
      int b = r / CC, c = r - b * CC;
      const float4 av = *(const float4*)(
          x + ((size_t)b * TT + s * CC + c) * DD + kc * 64 + kq * 4);
      *(float4*)&As[row][kq * 4] = av;
      const float4 wv = *(const float4*)(
          W_ih + ((size_t)s * HH + row) * DD + kc * 64 + kq * 4);
      *(float4*)&Bs[row][kq * 4] = wv;
    }
    __syncthreads();
#pragma unroll 4
    for (int k = 0; k < 64; k += 4) {
      float4 a[4], w[4];
#pragma unroll
      for (int i = 0; i < 4; ++i) a[i] = *(const float4*)&As[ty4 + i][k];
#pragma unroll
      for (int j = 0; j < 4; ++j) w[j] = *(const float4*)&Bs[tx4 + j][k];
#pragma unroll
      for (int i = 0; i < 4; ++i)
#pragma unroll
        for (int j = 0; j < 4; ++j)
          acc[i][j] += a[i].x * w[j].x + a[i].y * w[j].y +
                       a[i].z * w[j].z + a[i].w * w[j].w;
    }
    __syncthreads();
  }

  const float4 b1 = *(const float4*)(b_ih + s * HH + tx4);
  const float4 b2 = *(const float4*)(b_hh + s * HH + tx4);
#pragma unroll
  for (int i = 0; i < 4; ++i) {
    int r = r0 + ty4 + i;
    int b = r / CC, c = r - b * CC;
    float4 o;
    o.x = 2.f * (acc[i][0] + b1.x + b2.x);
    o.y = 2.f * (acc[i][1] + b1.y + b2.y);
    o.z = 2.f * (acc[i][2] + b1.z + b2.z);
    o.w = 2.f * (acc[i][3] + b1.w + b2.w);
    *(float4*)(xp + ((size_t)b * TT + s * CC + c) * HH + tx4) = o;
  }
}

// ---------------------------------------------------------------------------
// Kernel 2: recurrence, 4-wave K-split. R10 finding: single-wave issue rate
// is ~2.7ns/instr regardless of type -> the step is INSTRUCTION-count-bound
// (~95 instr = 275ns). Split the matvec K-dim across 4 waves:
//   wave w: partial_j = sum_{k in [16w,16w+16)} 2*W[j][k]*h[k]  (16 FMA)
//   write part[c&1][j][w]; __syncthreads();
//   ALL waves redundantly: read 4 partials (b128) + finish tanh + write hist.
// Redundant finish => every wave reads only values IT wrote => same-wave DS
// ordering suffices => only ONE barrier per step. part[] is parity-double-
// buffered to kill the leader(writes step c+1)/laggard(reads step c) race.
// Per-wave serial chain ~37 instr + 1 barrier.
// ---------------------------------------------------------------------------
__global__ __launch_bounds__(256, 1) void rnn_kernel(
    const float* __restrict__ xp, const float* __restrict__ W_hh,
    const float* __restrict__ fc_w, const float* __restrict__ fc_b,
    float* __restrict__ y) {
  __shared__ float hist[CC][68];
  __shared__ float part[2][64][4];
  const int b = blockIdx.x;
  const int tid = threadIdx.x;
  const int lane = tid & 63;
  const int w = tid >> 6;
  const int w16 = w * 16;

  hist[CC - 1][lane] = 0.f;  // h0 = 0 (every wave writes all 64 -> own-wave)

  float W16[16];
  for (int s = 0; s < SS; ++s) {
    // wave w, lane j holds 2*W_hh[s][j][16w..16w+16)  (16 VGPRs)
    const float* wr = W_hh + ((size_t)s * HH + lane) * HH + w16;
#pragma unroll
    for (int j = 0; j < 16; j += 4) {
      float4 v = *(const float4*)(wr + j);
      W16[j] = 2.f * v.x; W16[j + 1] = 2.f * v.y;
      W16[j + 2] = 2.f * v.z; W16[j + 3] = 2.f * v.w;
    }
    const float* xps = xp + ((size_t)b * TT + s * CC) * HH + lane;

    // 4-deep xp ring (probe<0> structure; off the critical path)
    float xq0 = xps[0 * HH];
    float xq1 = xps[1 * HH];
    float xq2 = xps[2 * HH];
    float xq3 = xps[3 * HH];

    for (int c4 = 0; c4 < 25; ++c4) {
#pragma unroll
      for (int u = 0; u < 4; ++u) {
        const int c = c4 * 4 + u;
        const int cp = (c == 0) ? CC - 1 : c - 1;
        const float xv = (u == 0) ? xq0 : (u == 1) ? xq1 : (u == 2) ? xq2 : xq3;
        // phase A: this wave's 16-wide K-slice (4 broadcast b128 reads)
        const float4 h0 = *(const float4*)&hist[cp][w16 + 0];
        const float4 h1 = *(const float4*)&hist[cp][w16 + 4];
        const float4 h2 = *(const float4*)&hist[cp][w16 + 8];
        const float4 h3 = *(const float4*)&hist[cp][w16 + 12];
        float pa, pb;
        pa  = W16[ 0] * h0.x; pb  = W16[ 1] * h0.y;
        pa += W16[ 2] * h0.z; pb += W16[ 3] * h0.w;
        pa += W16[ 4] * h1.x; pb += W16[ 5] * h1.y;
        pa += W16[ 6] * h1.z; pb += W16[ 7] * h1.w;
        pa += W16[ 8] * h2.x; pb += W16[ 9] * h2.y;
        pa += W16[10] * h2.z; pb += W16[11] * h2.w;
        pa += W16[12] * h3.x; pb += W16[13] * h3.y;
        pa += W16[14] * h3.z; pb += W16[15] * h3.w;
        part[c & 1][lane][w] = pa + pb;
        __syncthreads();
        // phase B: redundant finish on every wave (own-wave data only)
        const float4 pv = *(const float4*)&part[c & 1][lane][0];
        const float z2 = ((pv.x + pv.y) + (pv.z + pv.w)) + xv;  // = 2z
        const float e = __expf(z2);
        const float h = 1.f - 2.f * __builtin_amdgcn_rcpf(e + 1.f);
        hist[c][lane] = h;
        if (c4 < 24) {
          const float xn = xps[(c + 4) * HH];
          if (u == 0) xq0 = xn;
          else if (u == 1) xq1 = xn;
          else if (u == 2) xq2 = xn;
          else xq3 = xn;
        }
      }
    }

    // fused head: thread l<100 -> y[b, s*CC+l]; reads are own-wave-written
    // (every wave wrote every hist entry). No barrier needed: laggards can't
    // overwrite hist[0] until the step-0 barrier of segment s+1, which waits
    // for head completion of all waves.
    const float fb = fc_b[s];
    const float* fw = fc_w + s * HH;  // wave-uniform -> scalar loads
    if (tid < CC) {
      float z = fb;
#pragma unroll
      for (int i = 0; i < 64; i += 4) {
        const float4 hv = *(const float4*)&hist[tid][i];
        z += hv.x * fw[i] + hv.y * fw[i + 1] + hv.z * fw[i + 2] +
             hv.w * fw[i + 3];
      }
      y[(size_t)b * TT + s * CC + tid] =
          __builtin_amdgcn_rcpf(1.f + __expf(-z));
    }
  }
}

extern "C" void kernel_launch(void* const* d_in, const int* in_sizes, int n_in,
                              void* d_out, int out_size, void* d_ws,
                              size_t ws_size, hipStream_t stream) {
  const float* x    = (const float*)d_in[0];
  const float* W_ih = (const float*)d_in[1];
  const float* W_hh = (const float*)d_in[2];
  const float* b_ih = (const float*)d_in[3];
  const float* b_hh = (const float*)d_in[4];
  const float* fc_w = (const float*)d_in[5];
  const float* fc_b = (const float*)d_in[6];
  float* y  = (float*)d_out;
  float* xp = (float*)d_ws;  // [B][T][H] fp32 = 65.5 MB

  proj_kernel<<<dim3(400, 10), 256, 0, stream>>>(x, W_ih, b_ih, b_hh, xp);
  rnn_kernel<<<256, 256, 0, stream>>>(xp, W_hh, fc_w, fc_b, y);
}

// Round 12
// 394.950 us; speedup vs baseline: 1.4644x; 1.0129x over previous
//
#include <hip/hip_runtime.h>
#include <cstdint>

#define BB 256
#define TT 1000
#define DD 256
#define SS 10
#define HH 64
#define CC 100

// ---------------------------------------------------------------------------
// Kernel 1: input projection  xp[b,t,h] = 2*(x . W_ih + b_ih + b_hh)
// (unchanged; known 128 us)
// ---------------------------------------------------------------------------
__global__ __launch_bounds__(256) void proj_kernel(
    const float* __restrict__ x, const float* __restrict__ W_ih,
    const float* __restrict__ b_ih, const float* __restrict__ b_hh,
    float* __restrict__ xp) {
  __shared__ float As[64][68];
  __shared__ float Bs[64][68];
  const int s = blockIdx.y;
  const int r0 = blockIdx.x * 64;
  const int tid = threadIdx.x;
  const int ty = tid >> 4, tx = tid & 15;
  const int ty4 = ty * 4, tx4 = tx * 4;
  float acc[4][4] = {{0.f, 0.f, 0.f, 0.f}};

  for (int kc = 0; kc < 4; ++kc) {
#pragma unroll
    for (int m = 0; m < 4; ++m) {
      int f = m * 256 + tid;
      int row = f >> 4, kq = f & 15;
      int r = r0 + row;
      int b = r / CC, c = r - b * CC;
      const float4 av = *(const float4*)(
          x + ((size_t)b * TT + s * CC + c) * DD + kc * 64 + kq * 4);
      *(float4*)&As[row][kq * 4] = av;
      const float4 wv = *(const float4*)(
          W_ih + ((size_t)s * HH + row) * DD + kc * 64 + kq * 4);
      *(float4*)&Bs[row][kq * 4] = wv;
    }
    __syncthreads();
#pragma unroll 4
    for (int k = 0; k < 64; k += 4) {
      float4 a[4], w[4];
#pragma unroll
      for (int i = 0; i < 4; ++i) a[i] = *(const float4*)&As[ty4 + i][k];
#pragma unroll
      for (int j = 0; j < 4; ++j) w[j] = *(const float4*)&Bs[tx4 + j][k];
#pragma unroll
      for (int i = 0; i < 4; ++i)
#pragma unroll
        for (int j = 0; j < 4; ++j)
          acc[i][j] += a[i].x * w[j].x + a[i].y * w[j].y +
                       a[i].z * w[j].z + a[i].w * w[j].w;
    }
    __syncthreads();
  }

  const float4 b1 = *(const float4*)(b_ih + s * HH + tx4);
  const float4 b2 = *(const float4*)(b_hh + s * HH + tx4);
#pragma unroll
  for (int i = 0; i < 4; ++i) {
    int r = r0 + ty4 + i;
    int b = r / CC, c = r - b * CC;
    float4 o;
    o.x = 2.f * (acc[i][0] + b1.x + b2.x);
    o.y = 2.f * (acc[i][1] + b1.y + b2.y);
    o.z = 2.f * (acc[i][2] + b1.z + b2.z);
    o.w = 2.f * (acc[i][3] + b1.w + b2.w);
    *(float4*)(xp + ((size_t)b * TT + s * CC + c) * HH + tx4) = o;
  }
}

// ---------------------------------------------------------------------------
// Kernel 2: recurrence, 4-wave K-split (R11) + two fixes from R11 counters:
//  1) RAW BARRIER: asm "s_waitcnt lgkmcnt(0); s_barrier" instead of
//     __syncthreads(). __syncthreads drains vmcnt(0) too, which killed the
//     xp prefetch pipeline every step (~140ns/step exposed HBM latency).
//     lgkmcnt(0) alone makes the part-write visible; xp loads stay in flight.
//  2) part transposed to [2][4][64]: write part[p][w][lane] is lane-
//     consecutive (conflict-free; was 8-way = 6.1M conflict-cycles), reads
//     are 4x conflict-free ds_read_b32.
// Race-safety (unchanged from R11): parity double-buffered part; hist writes
// redundant on every wave so all hist reads are own-wave values; head reads
// complete before the next segment's step-0 barrier lets any wave overwrite.
// ---------------------------------------------------------------------------
__global__ __launch_bounds__(256, 1) void rnn_kernel(
    const float* __restrict__ xp, const float* __restrict__ W_hh,
    const float* __restrict__ fc_w, const float* __restrict__ fc_b,
    float* __restrict__ y) {
  __shared__ float hist[CC][68];
  __shared__ float part[2][4][64];
  const int b = blockIdx.x;
  const int tid = threadIdx.x;
  const int lane = tid & 63;
  const int w = tid >> 6;
  const int w16 = w * 16;

  hist[CC - 1][lane] = 0.f;  // h0 = 0 (every wave writes -> own-wave reads)

  float W16[16];
  for (int s = 0; s < SS; ++s) {
    // wave w, lane j holds 2*W_hh[s][j][16w..16w+16)
    const float* wr = W_hh + ((size_t)s * HH + lane) * HH + w16;
#pragma unroll
    for (int j = 0; j < 16; j += 4) {
      float4 v = *(const float4*)(wr + j);
      W16[j] = 2.f * v.x; W16[j + 1] = 2.f * v.y;
      W16[j + 2] = 2.f * v.z; W16[j + 3] = 2.f * v.w;
    }
    const float* xps = xp + ((size_t)b * TT + s * CC) * HH + lane;

    float xq0 = xps[0 * HH];
    float xq1 = xps[1 * HH];
    float xq2 = xps[2 * HH];
    float xq3 = xps[3 * HH];

    for (int c4 = 0; c4 < 25; ++c4) {
#pragma unroll
      for (int u = 0; u < 4; ++u) {
        const int c = c4 * 4 + u;
        const int cp = (c == 0) ? CC - 1 : c - 1;
        const float xv = (u == 0) ? xq0 : (u == 1) ? xq1 : (u == 2) ? xq2 : xq3;
        // phase A: this wave's 16-wide K-slice (4 broadcast b128 reads)
        const float4 h0 = *(const float4*)&hist[cp][w16 + 0];
        const float4 h1 = *(const float4*)&hist[cp][w16 + 4];
        const float4 h2 = *(const float4*)&hist[cp][w16 + 8];
        const float4 h3 = *(const float4*)&hist[cp][w16 + 12];
        float pa, pb;
        pa  = W16[ 0] * h0.x; pb  = W16[ 1] * h0.y;
        pa += W16[ 2] * h0.z; pb += W16[ 3] * h0.w;
        pa += W16[ 4] * h1.x; pb += W16[ 5] * h1.y;
        pa += W16[ 6] * h1.z; pb += W16[ 7] * h1.w;
        pa += W16[ 8] * h2.x; pb += W16[ 9] * h2.y;
        pa += W16[10] * h2.z; pb += W16[11] * h2.w;
        pa += W16[12] * h3.x; pb += W16[13] * h3.y;
        pa += W16[14] * h3.z; pb += W16[15] * h3.w;
        part[c & 1][w][lane] = pa + pb;  // lane-consecutive: conflict-free
        // sync: wait ONLY for LDS ops, then barrier. xp loads stay in flight.
        asm volatile("s_waitcnt lgkmcnt(0)\n\ts_barrier" ::: "memory");
        // phase B: redundant finish on every wave
        const float p0 = part[c & 1][0][lane];
        const float p1 = part[c & 1][1][lane];
        const float p2 = part[c & 1][2][lane];
        const float p3 = part[c & 1][3][lane];
        const float z2 = ((p0 + p1) + (p2 + p3)) + xv;  // = 2z
        const float e = __expf(z2);
        const float h = 1.f - 2.f * __builtin_amdgcn_rcpf(e + 1.f);
        hist[c][lane] = h;
        if (c4 < 24) {
          const float xn = xps[(c + 4) * HH];
          if (u == 0) xq0 = xn;
          else if (u == 1) xq1 = xn;
          else if (u == 2) xq2 = xn;
          else xq3 = xn;
        }
      }
    }

    // fused head: thread l<100 -> y[b, s*CC+l] (own-wave hist values;
    // protected from next-segment overwrite by the step-0 barrier)
    const float fb = fc_b[s];
    const float* fw = fc_w + s * HH;
    if (tid < CC) {
      float z = fb;
#pragma unroll
      for (int i = 0; i < 64; i += 4) {
        const float4 hv = *(const float4*)&hist[tid][i];
        z += hv.x * fw[i] + hv.y * fw[i + 1] + hv.z * fw[i + 2] +
             hv.w * fw[i + 3];
      }
      y[(size_t)b * TT + s * CC + tid] =
          __builtin_amdgcn_rcpf(1.f + __expf(-z));
    }
  }
}

extern "C" void kernel_launch(void* const* d_in, const int* in_sizes, int n_in,
                              void* d_out, int out_size, void* d_ws,
                              size_t ws_size, hipStream_t stream) {
  const float* x    = (const float*)d_in[0];
  const float* W_ih = (const float*)d_in[1];
  const float* W_hh = (const float*)d_in[2];
  const float* b_ih = (const float*)d_in[3];
  const float* b_hh = (const float*)d_in[4];
  const float* fc_w = (const float*)d_in[5];
  const float* fc_b = (const float*)d_in[6];
  float* y  = (float*)d_out;
  float* xp = (float*)d_ws;  // [B][T][H] fp32 = 65.5 MB

  proj_kernel<<<dim3(400, 10), 256, 0, stream>>>(x, W_ih, b_ih, b_hh, xp);
  rnn_kernel<<<256, 256, 0, stream>>>(xp, W_hh, fc_w, fc_b, y);
}

// Round 13
// 353.616 us; speedup vs baseline: 1.6355x; 1.1169x over previous
//
#include <hip/hip_runtime.h>
#include <cstdint>

#define BB 256
#define TT 1000
#define DD 256
#define SS 10
#define HH 64
#define CC 100

// 2 * log2(e): z2' = PRE*z so tanh(z) = 1 - 2/(exp2(z2')+1) -- v_exp_f32
// directly, no multiply on the serial chain.
#define PRE 2.885390081777927f

typedef float f32x2 __attribute__((ext_vector_type(2)));
typedef float f32x4 __attribute__((ext_vector_type(4)));

// ---------------------------------------------------------------------------
// Kernel 1: input projection  xp[b,t,h] = PRE*(x . W_ih + b_ih + b_hh)
// ---------------------------------------------------------------------------
__global__ __launch_bounds__(256) void proj_kernel(
    const float* __restrict__ x, const float* __restrict__ W_ih,
    const float* __restrict__ b_ih, const float* __restrict__ b_hh,
    float* __restrict__ xp) {
  __shared__ float As[64][68];
  __shared__ float Bs[64][68];
  const int s = blockIdx.y;
  const int r0 = blockIdx.x * 64;
  const int tid = threadIdx.x;
  const int ty = tid >> 4, tx = tid & 15;
  const int ty4 = ty * 4, tx4 = tx * 4;
  float acc[4][4] = {{0.f, 0.f, 0.f, 0.f}};

  for (int kc = 0; kc < 4; ++kc) {
#pragma unroll
    for (int m = 0; m < 4; ++m) {
      int f = m * 256 + tid;
      int row = f >> 4, kq = f & 15;
      int r = r0 + row;
      int b = r / CC, c = r - b * CC;
      const float4 av = *(const float4*)(
          x + ((size_t)b * TT + s * CC + c) * DD + kc * 64 + kq * 4);
      *(float4*)&As[row][kq * 4] = av;
      const float4 wv = *(const float4*)(
          W_ih + ((size_t)s * HH + row) * DD + kc * 64 + kq * 4);
      *(float4*)&Bs[row][kq * 4] = wv;
    }
    __syncthreads();
#pragma unroll 4
    for (int k = 0; k < 64; k += 4) {
      float4 a[4], w[4];
#pragma unroll
      for (int i = 0; i < 4; ++i) a[i] = *(const float4*)&As[ty4 + i][k];
#pragma unroll
      for (int j = 0; j < 4; ++j) w[j] = *(const float4*)&Bs[tx4 + j][k];
#pragma unroll
      for (int i = 0; i < 4; ++i)
#pragma unroll
        for (int j = 0; j < 4; ++j)
          acc[i][j] += a[i].x * w[j].x + a[i].y * w[j].y +
                       a[i].z * w[j].z + a[i].w * w[j].w;
    }
    __syncthreads();
  }

  const float4 b1 = *(const float4*)(b_ih + s * HH + tx4);
  const float4 b2 = *(const float4*)(b_hh + s * HH + tx4);
#pragma unroll
  for (int i = 0; i < 4; ++i) {
    int r = r0 + ty4 + i;
    int b = r / CC, c = r - b * CC;
    float4 o;
    o.x = PRE * (acc[i][0] + b1.x + b2.x);
    o.y = PRE * (acc[i][1] + b1.y + b2.y);
    o.z = PRE * (acc[i][2] + b1.z + b2.z);
    o.w = PRE * (acc[i][3] + b1.w + b2.w);
    *(float4*)(xp + ((size_t)b * TT + s * CC + c) * HH + tx4) = o;
  }
}

// ---------------------------------------------------------------------------
// Kernel 2: recurrence + fused head. SINGLE wave per b (R10 structure: no
// barrier, no cross-wave traffic -- proven 277us), with the 64 FMA slots
// packed into 32 v_pk_fma_f32 slots (float2 + __builtin_elementwise_fma).
// R10 lesson: this regime retires ~2.7ns per instruction SLOT regardless of
// type; pk_fma halves the dominant slot count. exp2-prescale removes the
// tanh-input multiply from the chain.
// ---------------------------------------------------------------------------
__global__ __launch_bounds__(64, 1) void rnn_kernel(
    const float* __restrict__ xp, const float* __restrict__ W_hh,
    const float* __restrict__ fc_w, const float* __restrict__ fc_b,
    float* __restrict__ y) {
  __shared__ float hist[CC][68];
  const int b = blockIdx.x;
  const int lane = threadIdx.x;
  hist[CC - 1][lane] = 0.f;  // h0 = 0, read via cp at s=0,c=0

  f32x2 Wp[32];
  float h = 0.f;
  for (int s = 0; s < SS; ++s) {
    const float* wr = W_hh + ((size_t)s * HH + lane) * HH;
#pragma unroll
    for (int j = 0; j < 16; ++j) {
      float4 v = *(const float4*)(wr + 4 * j);
      Wp[2 * j]     = (f32x2){PRE * v.x, PRE * v.y};
      Wp[2 * j + 1] = (f32x2){PRE * v.z, PRE * v.w};
    }
    const float* xps = xp + ((size_t)b * TT + s * CC) * HH + lane;

    float xq0 = xps[0 * HH];
    float xq1 = xps[1 * HH];
    float xq2 = xps[2 * HH];
    float xq3 = xps[3 * HH];

    for (int c4 = 0; c4 < 25; ++c4) {
#pragma unroll
      for (int u = 0; u < 4; ++u) {
        const int c = c4 * 4 + u;
        const int cp = (c == 0) ? CC - 1 : c - 1;
        const float xv = (u == 0) ? xq0 : (u == 1) ? xq1 : (u == 2) ? xq2 : xq3;
        f32x2 acc0 = {xv, 0.f};
        f32x2 acc1 = {0.f, 0.f};
#pragma unroll
        for (int j4 = 0; j4 < 16; ++j4) {
          const f32x4 hv = *(const f32x4*)&hist[cp][j4 * 4];
          const f32x2 lo = __builtin_shufflevector(hv, hv, 0, 1);
          const f32x2 hi = __builtin_shufflevector(hv, hv, 2, 3);
          acc0 = __builtin_elementwise_fma(Wp[2 * j4], lo, acc0);
          acc1 = __builtin_elementwise_fma(Wp[2 * j4 + 1], hi, acc1);
        }
        const f32x2 t = acc0 + acc1;
        const float z2 = t.x + t.y;          // = PRE * z
        const float e = __builtin_amdgcn_exp2f(z2);
        h = 1.f - 2.f * __builtin_amdgcn_rcpf(e + 1.f);
        hist[c][lane] = h;
        if (c4 < 24) {
          const float xn = xps[(c + 4) * HH];
          if (u == 0) xq0 = xn;
          else if (u == 1) xq1 = xn;
          else if (u == 2) xq2 = xn;
          else xq3 = xn;
        }
      }
    }

    // fused head for this segment: lane l -> y[b, s*CC + l]
    const float fb = fc_b[s];
    const float* fw = fc_w + s * HH;  // wave-uniform
#pragma unroll
    for (int base = 0; base < CC; base += 64) {
      int l = base + lane;
      if (l < CC) {
        float z = fb;
#pragma unroll
        for (int i = 0; i < 64; i += 4) {
          const float4 hv = *(const float4*)&hist[l][i];
          z += hv.x * fw[i] + hv.y * fw[i + 1] + hv.z * fw[i + 2] +
               hv.w * fw[i + 3];
        }
        y[(size_t)b * TT + s * CC + l] =
            __builtin_amdgcn_rcpf(1.f + __expf(-z));
      }
    }
  }
}

extern "C" void kernel_launch(void* const* d_in, const int* in_sizes, int n_in,
                              void* d_out, int out_size, void* d_ws,
                              size_t ws_size, hipStream_t stream) {
  const float* x    = (const float*)d_in[0];
  const float* W_ih = (const float*)d_in[1];
  const float* W_hh = (const float*)d_in[2];
  const float* b_ih = (const float*)d_in[3];
  const float* b_hh = (const float*)d_in[4];
  const float* fc_w = (const float*)d_in[5];
  const float* fc_b = (const float*)d_in[6];
  float* y  = (float*)d_out;
  float* xp = (float*)d_ws;  // [B][T][H] fp32 = 65.5 MB

  proj_kernel<<<dim3(400, 10), 256, 0, stream>>>(x, W_ih, b_ih, b_hh, xp);
  rnn_kernel<<<256, 64, 0, stream>>>(xp, W_hh, fc_w, fc_b, y);
}